// Round 4
// baseline (391.929 us; speedup 1.0000x reference)
//
#include <hip/hip_runtime.h>
#include <hip/hip_bf16.h>
#include <stdint.h>

#define BATCH   2048
#define NIN     2048
#define NGATES  8192
#define NCOL    16384   // NGATES*2

typedef short s16x8 __attribute__((ext_vector_type(8)));   // 8 bf16 (4 VGPRs)
typedef float f32x4 __attribute__((ext_vector_type(4)));

__device__ __forceinline__ void gload_lds16(const void* g, void* l) {
  __builtin_amdgcn_global_load_lds(
      (const __attribute__((address_space(1))) void*)g,
      (__attribute__((address_space(3))) void*)l,
      16, 0, 0);
}

__device__ __forceinline__ unsigned short f2bf(float f) {
  __hip_bfloat16 h = __float2bfloat16(f);
  return __builtin_bit_cast(unsigned short, h);
}
__device__ __forceinline__ float bf2f(unsigned int u) {
  return __bfloat162float(__builtin_bit_cast(__hip_bfloat16,
                                             (unsigned short)(u & 0xffff)));
}

// ---------------------------------------------------------------------------
// Kernel 1 (merged): blocks 0..4095: x fp32 -> bf16 row-major.
//                    blocks 4096..4127: per-gate bilinear coeffs from
//                    softmax(w[:,g]):  out = P0 + P1*A + P2*B + P3*A*B.
// ---------------------------------------------------------------------------
__global__ __launch_bounds__(256) void pre_k(const float4* __restrict__ x,
                                             ushort4* __restrict__ xb,
                                             const float* __restrict__ w,
                                             float4* __restrict__ coeff) {
  const int b = blockIdx.x;
  const int t = threadIdx.x;
  if (b < 4096) {
    const int i = b * 256 + t;
    float4 v = x[i];
    ushort4 h;
    h.x = f2bf(v.x); h.y = f2bf(v.y); h.z = f2bf(v.z); h.w = f2bf(v.w);
    xb[i] = h;
  } else {
    const int g = (b - 4096) * 256 + t;
    float e[16];
    float s = 0.f;
#pragma unroll
    for (int k = 0; k < 16; ++k) { e[k] = __expf(w[k * NGATES + g]); s += e[k]; }
    const float inv = 1.0f / s;
#pragma unroll
    for (int k = 0; k < 16; ++k) e[k] *= inv;
    const float P0 = e[8] + e[9] + e[10] + e[11] + e[12] + e[13] + e[14] + e[15];
    const float P1 = e[2] + e[3] + e[6] + e[7] - e[8] - e[9] - e[12] - e[13];
    const float P2 = e[4] + e[5] + e[6] + e[7] - e[8] - e[9] - e[10] - e[11];
    const float P3 = e[1] - e[2] - e[4] - 2.f * e[6] - e[7] + e[8] + 2.f * e[9]
                   + e[11] + e[13] - e[14];
    coeff[g] = make_float4(P0, P1, P2, P3);
  }
}

// ---------------------------------------------------------------------------
// Kernel 2 (v3): e = exp(c) bf16 transposed to bT[n][k]. Tile shrunk to
// 64n x 256k: LDS 36.6 KB -> 4 blocks/CU (was 2) for latency hiding;
// balanced 256B reads / 512B writes. Grid (NCOL/64, 8 k-eighths of 256).
// Col partial sums per eighth -> psums[8][NCOL] (GEMM folds 8).
// ---------------------------------------------------------------------------
__global__ __launch_bounds__(256) void softmax_t_k(const float* __restrict__ c,
                                                   unsigned short* __restrict__ bT,
                                                   float* __restrict__ psums) {
  extern __shared__ char sm3[];                 // 32768 tile + 4352 red
  char*  tile = sm3;                            // [64 rows][512 B]
  float* red  = (float*)(sm3 + 32768);          // [16][68]
  const int t = threadIdx.x;
  const int ng = (t & 15) * 4;   // 4 consecutive cols
  const int kg = t >> 4;         // 0..15: 8-row chunk
  const int n0 = blockIdx.x * 64;
  const int q  = blockIdx.y;     // 0..7: k-eighth of 256 rows
  const float* cb = c + (size_t)n0 + ng;
  float s0 = 0.f, s1 = 0.f, s2 = 0.f, s3 = 0.f;

  float4 v[8], nv[8];
  {
    const int r0 = q * 256 + kg * 8;
#pragma unroll
    for (int d = 0; d < 8; ++d)
      v[d] = *(const float4*)&cb[(size_t)(r0 + d) * NCOL];
  }
  for (int it = 0; it < 2; ++it) {
    if (it < 1) {
      const int r1 = q * 256 + 128 + kg * 8;
#pragma unroll
      for (int d = 0; d < 8; ++d)
        nv[d] = *(const float4*)&cb[(size_t)(r1 + d) * NCOL];
    }
    unsigned int u[4][4];   // [col][k-pair]
#pragma unroll
    for (int d2 = 0; d2 < 4; ++d2) {
      float4 e0 = v[2 * d2], e1 = v[2 * d2 + 1];
      unsigned int a0 = f2bf(__expf(e0.x)), b0 = f2bf(__expf(e1.x));
      unsigned int a1 = f2bf(__expf(e0.y)), b1 = f2bf(__expf(e1.y));
      unsigned int a2 = f2bf(__expf(e0.z)), b2 = f2bf(__expf(e1.z));
      unsigned int a3 = f2bf(__expf(e0.w)), b3 = f2bf(__expf(e1.w));
      s0 += bf2f(a0) + bf2f(b0);
      s1 += bf2f(a1) + bf2f(b1);
      s2 += bf2f(a2) + bf2f(b2);
      s3 += bf2f(a3) + bf2f(b3);
      u[0][d2] = a0 | (b0 << 16);
      u[1][d2] = a1 | (b1 << 16);
      u[2][d2] = a2 | (b2 << 16);
      u[3][d2] = a3 | (b3 << 16);
    }
    const int chunk = it * 16 + kg;             // 16B chunk (0..31) in 512B row
#pragma unroll
    for (int j = 0; j < 4; ++j) {
      const int row = ng + j;
      const int sw  = (chunk & ~7) | ((chunk ^ (row >> 2)) & 7);
      uint4 pk = make_uint4(u[j][0], u[j][1], u[j][2], u[j][3]);
      *(uint4*)&tile[row * 512 + sw * 16] = pk;
    }
    if (it < 1) {
#pragma unroll
      for (int d = 0; d < 8; ++d) v[d] = nv[d];
    }
  }
  red[kg * 68 + ng + 0] = s0;
  red[kg * 68 + ng + 1] = s1;
  red[kg * 68 + ng + 2] = s2;
  red[kg * 68 + ng + 3] = s3;
  __syncthreads();

  // Phase 2: wave wv -> rows wv*16..+15; two 512B row-halves per instruction.
  {
    const int wv = t >> 6;
    const int l  = t & 63;
#pragma unroll
    for (int r8 = 0; r8 < 8; ++r8) {
      const int row = wv * 16 + r8 * 2 + (l >> 5);
      const int ch  = l & 31;
      const int sw  = (ch & ~7) | ((ch ^ (row >> 2)) & 7);
      uint4 vv = *(const uint4*)&tile[row * 512 + sw * 16];
      *(uint4*)&bT[(size_t)(n0 + row) * NIN + q * 256 + ch * 8] = vv;
    }
  }
  if (t < 64) {
    float tot = 0.f;
#pragma unroll
    for (int k2 = 0; k2 < 16; ++k2) tot += red[k2 * 68 + t];
    psums[(size_t)q * NCOL + n0 + t] = tot;
  }
}

// ---------------------------------------------------------------------------
// Kernel 3: 256x256-tile 8-phase bf16 MFMA GEMM — now PERSISTENT 2-panel:
// grid 256 (exactly 1 block/CU, single execution round). Each block runs a
// flattened 64-tile virtual K-loop = two gate-panels (g0, g0+128) back to
// back; the panel switch is just a +256-bT-row shift in the B staging
// offsets, so the steady-state vmcnt(6)/barrier invariants hold across the
// boundary (tile tt+1 fully resident at end of tt). Panel-0 epilogue runs
// in the shadow of panel-1's in-flight prefetch — the old 2nd grid round's
// fill/drain/epilogue serialization disappears.
// ---------------------------------------------------------------------------
#define MFMA_B16(a, b, c) __builtin_amdgcn_mfma_f32_16x16x32_bf16(a, b, c, 0, 0, 0)

__global__ __launch_bounds__(512, 2) void gemm_gate_k(
    const unsigned short* __restrict__ xb,   // [2048][2048] bf16
    const unsigned short* __restrict__ bT,   // [16384][2048] bf16
    const float* __restrict__ ps,            // [8][16384] partial col sums
    const float4* __restrict__ coeff,        // [8192]
    float* __restrict__ out) {               // [2048][8192]
  extern __shared__ char smem[];             // 131072 B
  constexpr int NVT = 64;                    // 2 panels x (K/BK = 32)

  const int t  = threadIdx.x;                // 0..511
  const int l  = t & 63;
  const int w  = t >> 6;
  const int wm = w >> 2;                     // 0..1: M half
  const int wn = w & 3;                      // 0..3: N quarter
  const int fr = l & 15;
  const int cq = l >> 4;

  // 256 blocks: xcd = bid&7 (8 panels-pairs per XCD region), loc 0..31.
  const int bid = blockIdx.x;
  const int xcd = bid & 7;
  const int loc = bid >> 3;                  // 0..31
  const int m0  = (loc & 7) * 256;
  const int g0  = (xcd * 8 + (loc >> 3) * 2) * 128;   // panel 0; panel 1 = +128

  // ---- stage source offsets (elements), inverse-XOR-swizzled + B-permuted
  uint32_t offA[2][2], offB[2][2];           // [unit][round]
#pragma unroll
  for (int r = 0; r < 2; ++r) {
    const int idx = r * 512 + t;             // 0..1023 -> lds (row, slot)
    const int lr  = idx >> 3;
    const int ch  = (idx & 7) ^ (lr & 7);    // chunk stored at this slot
    const int rA  = (lr & 63) + ((lr >> 6) << 7);       // A1: rows 0-63,128-191
    offA[0][r] = (uint32_t)(m0 + rA) * NIN + ch * 8;
    offA[1][r] = offA[0][r] + (uint32_t)64 * NIN;       // A2: +64
    offB[0][r] = (uint32_t)(2 * (g0 + lr)) * NIN + ch * 8;  // even col
    offB[1][r] = offB[0][r] + NIN;                          // odd col
  }

  auto issueA = [&](int u, int tta) {        // A wraps: kb from (tta&31)
    const uint32_t kb = (uint32_t)(tta & 31) * 64;
    char* d = smem + ((tta & 1) << 16) + (u << 14) + t * 16;
    gload_lds16(xb + offA[u][0] + kb, d);
    gload_lds16(xb + offA[u][1] + kb, d + 8192);
  };
  auto issueB = [&](int u, int tta) {        // panel = tta>>5 -> +256 bT rows
    const uint32_t kb = (uint32_t)(tta & 31) * 64;
    const uint32_t pb = (uint32_t)(tta >> 5) * (256u * NIN);
    char* d = smem + ((tta & 1) << 16) + ((2 + u) << 14) + t * 16;
    gload_lds16(bT + offB[u][0] + pb + kb, d);
    gload_lds16(bT + offB[u][1] + pb + kb, d + 8192);
  };

  // ---- fragment read offsets (row*128, slot = chunk ^ (row&7))
  const int aob = (wm * 64 + fr) * 128;          // + unit*16384 + i*2048
  const int bob = 32768 + (wn * 32 + fr) * 128;  // + unit*16384 + j*2048
  const int sx0 = ((cq)     ^ (fr & 7)) * 16;    // ks=0 slot
  const int sx1 = ((cq + 4) ^ (fr & 7)) * 16;    // ks=1 slot

  f32x4 acc[8][4] = {};
  s16x8 af[8];     // current A half: 4 i x 2 ks
  s16x8 bfr[8];    // [0..3]=B1 (j=0,1 x ks), [4..7]=B2 (j=2,3 x ks)

  // epilogue: fold 8 psums eighths -> denominators, bilinear gate, store.
  auto epilogue = [&](int gp) {
#pragma unroll
    for (int j = 0; j < 2; ++j) {
      const int gate = gp + wn * 32 + j * 16 + fr;
      const int nA = 2 * gate, nB = 2 * gate + 1;
      float sA = 0.f, sB = 0.f;
#pragma unroll
      for (int qq = 0; qq < 8; ++qq) {
        sA += ps[qq * NCOL + nA];
        sB += ps[qq * NCOL + nB];
      }
      const float ivA = 1.0f / sA;
      const float ivB = 1.0f / sB;
      const float4 P = coeff[gate];
#pragma unroll
      for (int i = 0; i < 8; ++i) {
#pragma unroll
        for (int r = 0; r < 4; ++r) {
          const float A = acc[i][j][r]     * ivA;
          const float B = acc[i][j + 2][r] * ivB;
          const float res = P.x + P.y * A + P.z * B + P.w * A * B;
          const int m = m0 + wm * 128 + i * 16 + cq * 4 + r;
          out[(size_t)m * NGATES + gate] = res;
        }
      }
    }
  };

  // ---- prologue: tile0 full + tile1 {A1,B1,B2}; A2(1) comes at tt=0 ph0
  issueA(0, 0); issueA(1, 0); issueB(0, 0); issueB(1, 0);
  issueA(0, 1); issueB(0, 1); issueB(1, 1);
  asm volatile("s_waitcnt vmcnt(6)" ::: "memory");   // tile0 landed
  asm volatile("s_barrier" ::: "memory");

  for (int tt = 0; tt < NVT; ++tt) {
    char* rb = smem + ((tt & 1) << 16);

    // ===== phase 0: (i0-3, j0-1) — read A1 + B1, stage A2(tt+1)
#pragma unroll
    for (int i = 0; i < 4; ++i) {
      af[i * 2 + 0] = *(const s16x8*)(rb + aob + i * 2048 + sx0);
      af[i * 2 + 1] = *(const s16x8*)(rb + aob + i * 2048 + sx1);
    }
#pragma unroll
    for (int j = 0; j < 2; ++j) {
      bfr[j * 2 + 0] = *(const s16x8*)(rb + bob + j * 2048 + sx0);
      bfr[j * 2 + 1] = *(const s16x8*)(rb + bob + j * 2048 + sx1);
    }
    if (tt + 1 < NVT) issueA(1, tt + 1);
    asm volatile("s_waitcnt lgkmcnt(8)" ::: "memory");  // 12 ds_reads issued
    asm volatile("s_barrier" ::: "memory");
    asm volatile("s_waitcnt lgkmcnt(0)" ::: "memory");
    __builtin_amdgcn_s_setprio(1);
#pragma unroll
    for (int i = 0; i < 4; ++i)
#pragma unroll
      for (int j = 0; j < 2; ++j) {
        acc[i][j] = MFMA_B16(af[i * 2 + 0], bfr[j * 2 + 0], acc[i][j]);
        acc[i][j] = MFMA_B16(af[i * 2 + 1], bfr[j * 2 + 1], acc[i][j]);
      }
    __builtin_amdgcn_s_setprio(0);
    asm volatile("s_barrier" ::: "memory");

    // ===== phase 1: (i0-3, j2-3) — read B2, stage A1(tt+2)
#pragma unroll
    for (int j = 0; j < 2; ++j) {
      bfr[4 + j * 2 + 0] = *(const s16x8*)(rb + bob + 16384 + j * 2048 + sx0);
      bfr[4 + j * 2 + 1] = *(const s16x8*)(rb + bob + 16384 + j * 2048 + sx1);
    }
    if (tt + 2 < NVT) issueA(0, tt + 2);
    asm volatile("s_barrier" ::: "memory");
    asm volatile("s_waitcnt lgkmcnt(0)" ::: "memory");
    __builtin_amdgcn_s_setprio(1);
#pragma unroll
    for (int i = 0; i < 4; ++i)
#pragma unroll
      for (int j = 0; j < 2; ++j) {
        acc[i][2 + j] = MFMA_B16(af[i * 2 + 0], bfr[4 + j * 2 + 0], acc[i][2 + j]);
        acc[i][2 + j] = MFMA_B16(af[i * 2 + 1], bfr[4 + j * 2 + 1], acc[i][2 + j]);
      }
    __builtin_amdgcn_s_setprio(0);
    asm volatile("s_barrier" ::: "memory");

    // ===== phase 2: (i4-7, j2-3) — read A2 into af, stage B1(tt+2)
#pragma unroll
    for (int i = 0; i < 4; ++i) {
      af[i * 2 + 0] = *(const s16x8*)(rb + 16384 + aob + i * 2048 + sx0);
      af[i * 2 + 1] = *(const s16x8*)(rb + 16384 + aob + i * 2048 + sx1);
    }
    if (tt + 2 < NVT) issueB(0, tt + 2);
    asm volatile("s_barrier" ::: "memory");
    asm volatile("s_waitcnt lgkmcnt(0)" ::: "memory");
    __builtin_amdgcn_s_setprio(1);
#pragma unroll
    for (int i = 0; i < 4; ++i)
#pragma unroll
      for (int j = 0; j < 2; ++j) {
        acc[4 + i][2 + j] = MFMA_B16(af[i * 2 + 0], bfr[4 + j * 2 + 0], acc[4 + i][2 + j]);
        acc[4 + i][2 + j] = MFMA_B16(af[i * 2 + 1], bfr[4 + j * 2 + 1], acc[4 + i][2 + j]);
      }
    __builtin_amdgcn_s_setprio(0);
    asm volatile("s_barrier" ::: "memory");

    // ===== phase 3: (i4-7, j0-1) — no reads, stage B2(tt+2), counted vmcnt
    if (tt + 2 < NVT) issueB(1, tt + 2);
    asm volatile("s_barrier" ::: "memory");
    asm volatile("s_waitcnt lgkmcnt(0)" ::: "memory");
    __builtin_amdgcn_s_setprio(1);
#pragma unroll
    for (int i = 0; i < 4; ++i)
#pragma unroll
      for (int j = 0; j < 2; ++j) {
        acc[4 + i][j] = MFMA_B16(af[i * 2 + 0], bfr[j * 2 + 0], acc[4 + i][j]);
        acc[4 + i][j] = MFMA_B16(af[i * 2 + 1], bfr[j * 2 + 1], acc[4 + i][j]);
      }
    __builtin_amdgcn_s_setprio(0);
    if (tt < NVT - 2) {
      asm volatile("s_waitcnt vmcnt(6)" ::: "memory");  // tile tt+1 resident
    } else {
      asm volatile("s_waitcnt vmcnt(0)" ::: "memory");  // drain tail
    }
    asm volatile("s_barrier" ::: "memory");

    // ---- panel boundary: write panel 0, reset acc, continue pipeline
    if (tt == 31) {
      epilogue(g0);
#pragma unroll
      for (int i = 0; i < 8; ++i)
#pragma unroll
        for (int j = 0; j < 4; ++j) acc[i][j] = (f32x4){0.f, 0.f, 0.f, 0.f};
    }
  }

  epilogue(g0 + 128);
}

// ---------------------------------------------------------------------------
extern "C" void kernel_launch(void* const* d_in, const int* in_sizes, int n_in,
                              void* d_out, int out_size, void* d_ws,
                              size_t ws_size, hipStream_t stream) {
  const float* x = (const float*)d_in[0];   // [2048][2048]
  const float* w = (const float*)d_in[1];   // [16][8192]
  const float* c = (const float*)d_in[2];   // [2048][8192][2]
  float* out = (float*)d_out;               // [2048][8192]
  char* ws = (char*)d_ws;

  unsigned short* xb = (unsigned short*)(ws);               // 8,388,608 B
  unsigned short* bT = (unsigned short*)(ws + 8388608);     // 67,108,864 B
  float*          psv = (float*)(ws + 75497472);            // 524,288 B
  float4*         cf = (float4*)(ws + 76021760);            // 131,072 B

  static bool attr_done = false;
  if (!attr_done) {
    (void)hipFuncSetAttribute(reinterpret_cast<const void*>(gemm_gate_k),
                              hipFuncAttributeMaxDynamicSharedMemorySize,
                              131072);
    (void)hipFuncSetAttribute(reinterpret_cast<const void*>(softmax_t_k),
                              hipFuncAttributeMaxDynamicSharedMemorySize,
                              37120);
    attr_done = true;
  }

  pre_k<<<4128, 256, 0, stream>>>((const float4*)x, (ushort4*)xb, w, cf);
  dim3 sg(NCOL / 64, 8);
  softmax_t_k<<<sg, 256, 37120, stream>>>(c, bT, psv);
  gemm_gate_k<<<256, 512, 131072, stream>>>(xb, bT, psv, cf, out);
}

// Round 5
// 358.680 us; speedup vs baseline: 1.0927x; 1.0927x over previous
//
#include <hip/hip_runtime.h>
#include <hip/hip_bf16.h>
#include <stdint.h>

#define BATCH   2048
#define NIN     2048
#define NGATES  8192
#define NCOL    16384   // NGATES*2

typedef short s16x8 __attribute__((ext_vector_type(8)));   // 8 bf16 (4 VGPRs)
typedef float f32x4 __attribute__((ext_vector_type(4)));

__device__ __forceinline__ void gload_lds16(const void* g, void* l) {
  __builtin_amdgcn_global_load_lds(
      (const __attribute__((address_space(1))) void*)g,
      (__attribute__((address_space(3))) void*)l,
      16, 0, 0);
}

__device__ __forceinline__ unsigned short f2bf(float f) {
  __hip_bfloat16 h = __float2bfloat16(f);
  return __builtin_bit_cast(unsigned short, h);
}
__device__ __forceinline__ float bf2f(unsigned int u) {
  return __bfloat162float(__builtin_bit_cast(__hip_bfloat16,
                                             (unsigned short)(u & 0xffff)));
}

// ---------------------------------------------------------------------------
// Kernel 1 (merged): blocks 0..4095: x fp32 -> bf16 row-major.
//                    blocks 4096..4127: per-gate bilinear coeffs from
//                    softmax(w[:,g]):  out = P0 + P1*A + P2*B + P3*A*B.
// ---------------------------------------------------------------------------
__global__ __launch_bounds__(256) void pre_k(const float4* __restrict__ x,
                                             ushort4* __restrict__ xb,
                                             const float* __restrict__ w,
                                             float4* __restrict__ coeff) {
  const int b = blockIdx.x;
  const int t = threadIdx.x;
  if (b < 4096) {
    const int i = b * 256 + t;
    float4 v = x[i];
    ushort4 h;
    h.x = f2bf(v.x); h.y = f2bf(v.y); h.z = f2bf(v.z); h.w = f2bf(v.w);
    xb[i] = h;
  } else {
    const int g = (b - 4096) * 256 + t;
    float e[16];
    float s = 0.f;
#pragma unroll
    for (int k = 0; k < 16; ++k) { e[k] = __expf(w[k * NGATES + g]); s += e[k]; }
    const float inv = 1.0f / s;
#pragma unroll
    for (int k = 0; k < 16; ++k) e[k] *= inv;
    const float P0 = e[8] + e[9] + e[10] + e[11] + e[12] + e[13] + e[14] + e[15];
    const float P1 = e[2] + e[3] + e[6] + e[7] - e[8] - e[9] - e[12] - e[13];
    const float P2 = e[4] + e[5] + e[6] + e[7] - e[8] - e[9] - e[10] - e[11];
    const float P3 = e[1] - e[2] - e[4] - 2.f * e[6] - e[7] + e[8] + 2.f * e[9]
                   + e[11] + e[13] - e[14];
    coeff[g] = make_float4(P0, P1, P2, P3);
  }
}

// ---------------------------------------------------------------------------
// Kernel 2 (v3, unchanged from round 4 — measured neutral-to-positive):
// e = exp(c) bf16 transposed to bT[n][k]. 64n x 256k tile, 36.6 KB LDS,
// 4 blocks/CU. Grid (NCOL/64, 8 k-eighths of 256). Col partial sums per
// eighth -> psums[8][NCOL] (GEMM folds 8).
// ---------------------------------------------------------------------------
__global__ __launch_bounds__(256) void softmax_t_k(const float* __restrict__ c,
                                                   unsigned short* __restrict__ bT,
                                                   float* __restrict__ psums) {
  extern __shared__ char sm3[];                 // 32768 tile + 4352 red
  char*  tile = sm3;                            // [64 rows][512 B]
  float* red  = (float*)(sm3 + 32768);          // [16][68]
  const int t = threadIdx.x;
  const int ng = (t & 15) * 4;   // 4 consecutive cols
  const int kg = t >> 4;         // 0..15: 8-row chunk
  const int n0 = blockIdx.x * 64;
  const int q  = blockIdx.y;     // 0..7: k-eighth of 256 rows
  const float* cb = c + (size_t)n0 + ng;
  float s0 = 0.f, s1 = 0.f, s2 = 0.f, s3 = 0.f;

  float4 v[8], nv[8];
  {
    const int r0 = q * 256 + kg * 8;
#pragma unroll
    for (int d = 0; d < 8; ++d)
      v[d] = *(const float4*)&cb[(size_t)(r0 + d) * NCOL];
  }
  for (int it = 0; it < 2; ++it) {
    if (it < 1) {
      const int r1 = q * 256 + 128 + kg * 8;
#pragma unroll
      for (int d = 0; d < 8; ++d)
        nv[d] = *(const float4*)&cb[(size_t)(r1 + d) * NCOL];
    }
    unsigned int u[4][4];   // [col][k-pair]
#pragma unroll
    for (int d2 = 0; d2 < 4; ++d2) {
      float4 e0 = v[2 * d2], e1 = v[2 * d2 + 1];
      unsigned int a0 = f2bf(__expf(e0.x)), b0 = f2bf(__expf(e1.x));
      unsigned int a1 = f2bf(__expf(e0.y)), b1 = f2bf(__expf(e1.y));
      unsigned int a2 = f2bf(__expf(e0.z)), b2 = f2bf(__expf(e1.z));
      unsigned int a3 = f2bf(__expf(e0.w)), b3 = f2bf(__expf(e1.w));
      s0 += bf2f(a0) + bf2f(b0);
      s1 += bf2f(a1) + bf2f(b1);
      s2 += bf2f(a2) + bf2f(b2);
      s3 += bf2f(a3) + bf2f(b3);
      u[0][d2] = a0 | (b0 << 16);
      u[1][d2] = a1 | (b1 << 16);
      u[2][d2] = a2 | (b2 << 16);
      u[3][d2] = a3 | (b3 << 16);
    }
    const int chunk = it * 16 + kg;             // 16B chunk (0..31) in 512B row
#pragma unroll
    for (int j = 0; j < 4; ++j) {
      const int row = ng + j;
      const int sw  = (chunk & ~7) | ((chunk ^ (row >> 2)) & 7);
      uint4 pk = make_uint4(u[j][0], u[j][1], u[j][2], u[j][3]);
      *(uint4*)&tile[row * 512 + sw * 16] = pk;
    }
    if (it < 1) {
#pragma unroll
      for (int d = 0; d < 8; ++d) v[d] = nv[d];
    }
  }
  red[kg * 68 + ng + 0] = s0;
  red[kg * 68 + ng + 1] = s1;
  red[kg * 68 + ng + 2] = s2;
  red[kg * 68 + ng + 3] = s3;
  __syncthreads();

  // Phase 2: wave wv -> rows wv*16..+15; two 512B row-halves per instruction.
  {
    const int wv = t >> 6;
    const int l  = t & 63;
#pragma unroll
    for (int r8 = 0; r8 < 8; ++r8) {
      const int row = wv * 16 + r8 * 2 + (l >> 5);
      const int ch  = l & 31;
      const int sw  = (ch & ~7) | ((ch ^ (row >> 2)) & 7);
      uint4 vv = *(const uint4*)&tile[row * 512 + sw * 16];
      *(uint4*)&bT[(size_t)(n0 + row) * NIN + q * 256 + ch * 8] = vv;
    }
  }
  if (t < 64) {
    float tot = 0.f;
#pragma unroll
    for (int k2 = 0; k2 < 16; ++k2) tot += red[k2 * 68 + t];
    psums[(size_t)q * NCOL + n0 + t] = tot;
  }
}

// ---------------------------------------------------------------------------
// Kernel 3: 256x256-tile 8-phase bf16 MFMA GEMM — persistent 2-panel,
// SPILL-SAFE structure (round-4 post-mortem: mid-loop epilogue caused
// ~100MB scratch spills, WRITE_SIZE 98->169MB). The inner 32-tile loop is
// the bit-identical round-3 proven body (134us, VGPR 116, 0 spills).
// Panel boundary is OUTSIDE it: drain panel 0, issue panel-1 prologue,
// run panel-0 epilogue while those 14 loads are in flight (fill hides
// under epilogue), reset acc, vmcnt(6)+barrier, run loop again.
// Grid 256 = exactly 1 block/CU: single execution round.
// ---------------------------------------------------------------------------
#define MFMA_B16(a, b, c) __builtin_amdgcn_mfma_f32_16x16x32_bf16(a, b, c, 0, 0, 0)

__global__ __launch_bounds__(512, 2) void gemm_gate_k(
    const unsigned short* __restrict__ xb,   // [2048][2048] bf16
    const unsigned short* __restrict__ bT,   // [16384][2048] bf16
    const float* __restrict__ ps,            // [8][16384] partial col sums
    const float4* __restrict__ coeff,        // [8192]
    float* __restrict__ out) {               // [2048][8192]
  extern __shared__ char smem[];             // 131072 B
  constexpr int NT = 32;                     // K / BK = 2048/64

  const int t  = threadIdx.x;                // 0..511
  const int l  = t & 63;
  const int w  = t >> 6;
  const int wm = w >> 2;                     // 0..1: M half
  const int wn = w & 3;                      // 0..3: N quarter
  const int fr = l & 15;
  const int cq = l >> 4;

  // 256 blocks: xcd = bid&7, loc 0..31 -> 8 m-tiles x 4 panel-pairs.
  const int bid = blockIdx.x;
  const int xcd = bid & 7;
  const int loc = bid >> 3;                  // 0..31
  const int m0  = (loc & 7) * 256;
  const int g0  = (xcd * 8 + (loc >> 3) * 2) * 128;   // panel 0; panel 1 = +128

  // ---- stage source offsets (elements), inverse-XOR-swizzled + B-permuted
  uint32_t offA[2][2], offB[2][2];           // [unit][round]
#pragma unroll
  for (int r = 0; r < 2; ++r) {
    const int idx = r * 512 + t;             // 0..1023 -> lds (row, slot)
    const int lr  = idx >> 3;
    const int ch  = (idx & 7) ^ (lr & 7);    // chunk stored at this slot
    const int rA  = (lr & 63) + ((lr >> 6) << 7);       // A1: rows 0-63,128-191
    offA[0][r] = (uint32_t)(m0 + rA) * NIN + ch * 8;
    offA[1][r] = offA[0][r] + (uint32_t)64 * NIN;       // A2: +64
    offB[0][r] = (uint32_t)(2 * (g0 + lr)) * NIN + ch * 8;  // even col
    offB[1][r] = offB[0][r] + NIN;                          // odd col
  }

  uint32_t pbB = 0;    // B panel offset: 0 (panel 0) or 256*NIN (panel 1)

  auto issueA = [&](int u, int kt) {
    char* d = smem + ((kt & 1) << 16) + (u << 14) + t * 16;
    gload_lds16(xb + offA[u][0] + kt * 64, d);
    gload_lds16(xb + offA[u][1] + kt * 64, d + 8192);
  };
  auto issueB = [&](int u, int kt) {
    char* d = smem + ((kt & 1) << 16) + ((2 + u) << 14) + t * 16;
    gload_lds16(bT + offB[u][0] + pbB + kt * 64, d);
    gload_lds16(bT + offB[u][1] + pbB + kt * 64, d + 8192);
  };
  auto prologue = [&]() {      // tile0 full + tile1 {A1,B1,B2}
    issueA(0, 0); issueA(1, 0); issueB(0, 0); issueB(1, 0);
    issueA(0, 1); issueB(0, 1); issueB(1, 1);
  };

  // ---- fragment read offsets (row*128, slot = chunk ^ (row&7))
  const int aob = (wm * 64 + fr) * 128;          // + unit*16384 + i*2048
  const int bob = 32768 + (wn * 32 + fr) * 128;  // + unit*16384 + j*2048
  const int sx0 = ((cq)     ^ (fr & 7)) * 16;    // ks=0 slot
  const int sx1 = ((cq + 4) ^ (fr & 7)) * 16;    // ks=1 slot

  f32x4 acc[8][4] = {};
  s16x8 af[8];     // current A half: 4 i x 2 ks
  s16x8 bfr[8];    // [0..3]=B1 (j=0,1 x ks), [4..7]=B2 (j=2,3 x ks)

  // ---- the proven round-3 32-tile pipelined loop (verbatim body)
  auto run_panel = [&]() {
    for (int kt = 0; kt < NT; ++kt) {
      char* rb = smem + ((kt & 1) << 16);

      // ===== phase 0: (i0-3, j0-1) — read A1 + B1, stage A2(kt+1)
#pragma unroll
      for (int i = 0; i < 4; ++i) {
        af[i * 2 + 0] = *(const s16x8*)(rb + aob + i * 2048 + sx0);
        af[i * 2 + 1] = *(const s16x8*)(rb + aob + i * 2048 + sx1);
      }
#pragma unroll
      for (int j = 0; j < 2; ++j) {
        bfr[j * 2 + 0] = *(const s16x8*)(rb + bob + j * 2048 + sx0);
        bfr[j * 2 + 1] = *(const s16x8*)(rb + bob + j * 2048 + sx1);
      }
      if (kt + 1 < NT) issueA(1, kt + 1);
      asm volatile("s_barrier" ::: "memory");
      asm volatile("s_waitcnt lgkmcnt(0)" ::: "memory");
      __builtin_amdgcn_s_setprio(1);
#pragma unroll
      for (int i = 0; i < 4; ++i)
#pragma unroll
        for (int j = 0; j < 2; ++j) {
          acc[i][j] = MFMA_B16(af[i * 2 + 0], bfr[j * 2 + 0], acc[i][j]);
          acc[i][j] = MFMA_B16(af[i * 2 + 1], bfr[j * 2 + 1], acc[i][j]);
        }
      __builtin_amdgcn_s_setprio(0);
      asm volatile("s_barrier" ::: "memory");

      // ===== phase 1: (i0-3, j2-3) — read B2, stage A1(kt+2)
#pragma unroll
      for (int j = 0; j < 2; ++j) {
        bfr[4 + j * 2 + 0] = *(const s16x8*)(rb + bob + 16384 + j * 2048 + sx0);
        bfr[4 + j * 2 + 1] = *(const s16x8*)(rb + bob + 16384 + j * 2048 + sx1);
      }
      if (kt + 2 < NT) issueA(0, kt + 2);
      asm volatile("s_barrier" ::: "memory");
      asm volatile("s_waitcnt lgkmcnt(0)" ::: "memory");
      __builtin_amdgcn_s_setprio(1);
#pragma unroll
      for (int i = 0; i < 4; ++i)
#pragma unroll
        for (int j = 0; j < 2; ++j) {
          acc[i][2 + j] = MFMA_B16(af[i * 2 + 0], bfr[4 + j * 2 + 0], acc[i][2 + j]);
          acc[i][2 + j] = MFMA_B16(af[i * 2 + 1], bfr[4 + j * 2 + 1], acc[i][2 + j]);
        }
      __builtin_amdgcn_s_setprio(0);
      asm volatile("s_barrier" ::: "memory");

      // ===== phase 2: (i4-7, j2-3) — read A2 into af, stage B1(kt+2)
#pragma unroll
      for (int i = 0; i < 4; ++i) {
        af[i * 2 + 0] = *(const s16x8*)(rb + 16384 + aob + i * 2048 + sx0);
        af[i * 2 + 1] = *(const s16x8*)(rb + 16384 + aob + i * 2048 + sx1);
      }
      if (kt + 2 < NT) issueB(0, kt + 2);
      asm volatile("s_barrier" ::: "memory");
      asm volatile("s_waitcnt lgkmcnt(0)" ::: "memory");
      __builtin_amdgcn_s_setprio(1);
#pragma unroll
      for (int i = 0; i < 4; ++i)
#pragma unroll
        for (int j = 0; j < 2; ++j) {
          acc[4 + i][2 + j] = MFMA_B16(af[i * 2 + 0], bfr[4 + j * 2 + 0], acc[4 + i][2 + j]);
          acc[4 + i][2 + j] = MFMA_B16(af[i * 2 + 1], bfr[4 + j * 2 + 1], acc[4 + i][2 + j]);
        }
      __builtin_amdgcn_s_setprio(0);
      asm volatile("s_barrier" ::: "memory");

      // ===== phase 3: (i4-7, j0-1) — no reads, stage B2(kt+2), counted vmcnt
      if (kt + 2 < NT) issueB(1, kt + 2);
      asm volatile("s_barrier" ::: "memory");
      asm volatile("s_waitcnt lgkmcnt(0)" ::: "memory");
      __builtin_amdgcn_s_setprio(1);
#pragma unroll
      for (int i = 0; i < 4; ++i)
#pragma unroll
        for (int j = 0; j < 2; ++j) {
          acc[4 + i][j] = MFMA_B16(af[i * 2 + 0], bfr[j * 2 + 0], acc[4 + i][j]);
          acc[4 + i][j] = MFMA_B16(af[i * 2 + 1], bfr[j * 2 + 1], acc[4 + i][j]);
        }
      __builtin_amdgcn_s_setprio(0);
      if (kt < NT - 2) {
        asm volatile("s_waitcnt vmcnt(6)" ::: "memory");  // tile kt+1 resident
      } else {
        asm volatile("s_waitcnt vmcnt(0)" ::: "memory");  // drain tail
      }
      asm volatile("s_barrier" ::: "memory");
    }
  };

  // epilogue: fold 8 psums eighths -> denominators, bilinear gate, store.
  auto epilogue = [&](int gp) {
#pragma unroll
    for (int j = 0; j < 2; ++j) {
      const int gate = gp + wn * 32 + j * 16 + fr;
      const int nA = 2 * gate, nB = 2 * gate + 1;
      float sA = 0.f, sB = 0.f;
#pragma unroll
      for (int qq = 0; qq < 8; ++qq) {
        sA += ps[qq * NCOL + nA];
        sB += ps[qq * NCOL + nB];
      }
      const float ivA = 1.0f / sA;
      const float ivB = 1.0f / sB;
      const float4 P = coeff[gate];
#pragma unroll
      for (int i = 0; i < 8; ++i) {
#pragma unroll
        for (int r = 0; r < 4; ++r) {
          const float A = acc[i][j][r]     * ivA;
          const float B = acc[i][j + 2][r] * ivB;
          const float res = P.x + P.y * A + P.z * B + P.w * A * B;
          const int m = m0 + wm * 128 + i * 16 + cq * 4 + r;
          out[(size_t)m * NGATES + gate] = res;
        }
      }
    }
  };

  // ================= panel 0 =================
  prologue();
  asm volatile("s_waitcnt vmcnt(6)" ::: "memory");   // tile0 landed
  asm volatile("s_barrier" ::: "memory");
  run_panel();

  // ======== panel boundary: overlap panel-1 fill with panel-0 epilogue ====
  pbB = 256u * NIN;          // B offsets -> gates g0+128..g0+255
  prologue();                // 14 loads in flight...
  epilogue(g0);              // ...hidden under epilogue compute + stores
#pragma unroll
  for (int i = 0; i < 8; ++i)
#pragma unroll
    for (int j = 0; j < 4; ++j) acc[i][j] = (f32x4){0.f, 0.f, 0.f, 0.f};
  asm volatile("s_waitcnt vmcnt(6)" ::: "memory");   // tile0 of panel 1 landed
  asm volatile("s_barrier" ::: "memory");

  // ================= panel 1 =================
  run_panel();
  epilogue(g0 + 128);
}

// ---------------------------------------------------------------------------
extern "C" void kernel_launch(void* const* d_in, const int* in_sizes, int n_in,
                              void* d_out, int out_size, void* d_ws,
                              size_t ws_size, hipStream_t stream) {
  const float* x = (const float*)d_in[0];   // [2048][2048]
  const float* w = (const float*)d_in[1];   // [16][8192]
  const float* c = (const float*)d_in[2];   // [2048][8192][2]
  float* out = (float*)d_out;               // [2048][8192]
  char* ws = (char*)d_ws;

  unsigned short* xb = (unsigned short*)(ws);               // 8,388,608 B
  unsigned short* bT = (unsigned short*)(ws + 8388608);     // 67,108,864 B
  float*          psv = (float*)(ws + 75497472);            // 524,288 B
  float4*         cf = (float4*)(ws + 76021760);            // 131,072 B

  static bool attr_done = false;
  if (!attr_done) {
    (void)hipFuncSetAttribute(reinterpret_cast<const void*>(gemm_gate_k),
                              hipFuncAttributeMaxDynamicSharedMemorySize,
                              131072);
    (void)hipFuncSetAttribute(reinterpret_cast<const void*>(softmax_t_k),
                              hipFuncAttributeMaxDynamicSharedMemorySize,
                              37120);
    attr_done = true;
  }

  pre_k<<<4128, 256, 0, stream>>>((const float4*)x, (ushort4*)xb, w, cf);
  dim3 sg(NCOL / 64, 8);
  softmax_t_k<<<sg, 256, 37120, stream>>>(c, bT, psv);
  gemm_gate_k<<<256, 512, 131072, stream>>>(xb, bT, psv, cf, out);
}

// Round 6
// 348.859 us; speedup vs baseline: 1.1235x; 1.0282x over previous
//
#include <hip/hip_runtime.h>
#include <hip/hip_bf16.h>
#include <stdint.h>

#define BATCH   2048
#define NIN     2048
#define NGATES  8192
#define NCOL    16384   // NGATES*2

typedef short s16x8 __attribute__((ext_vector_type(8)));   // 8 bf16 (4 VGPRs)
typedef float f32x4 __attribute__((ext_vector_type(4)));

__device__ __forceinline__ void gload_lds16(const void* g, void* l) {
  __builtin_amdgcn_global_load_lds(
      (const __attribute__((address_space(1))) void*)g,
      (__attribute__((address_space(3))) void*)l,
      16, 0, 0);
}

__device__ __forceinline__ unsigned short f2bf(float f) {
  __hip_bfloat16 h = __float2bfloat16(f);
  return __builtin_bit_cast(unsigned short, h);
}
__device__ __forceinline__ float bf2f(unsigned int u) {
  return __bfloat162float(__builtin_bit_cast(__hip_bfloat16,
                                             (unsigned short)(u & 0xffff)));
}

// ---------------------------------------------------------------------------
// Kernel 1 (merged): blocks 0..4095: x fp32 -> bf16 row-major.
//                    blocks 4096..4127: per-gate bilinear coeffs from
//                    softmax(w[:,g]):  out = P0 + P1*A + P2*B + P3*A*B.
// ---------------------------------------------------------------------------
__global__ __launch_bounds__(256) void pre_k(const float4* __restrict__ x,
                                             ushort4* __restrict__ xb,
                                             const float* __restrict__ w,
                                             float4* __restrict__ coeff) {
  const int b = blockIdx.x;
  const int t = threadIdx.x;
  if (b < 4096) {
    const int i = b * 256 + t;
    float4 v = x[i];
    ushort4 h;
    h.x = f2bf(v.x); h.y = f2bf(v.y); h.z = f2bf(v.z); h.w = f2bf(v.w);
    xb[i] = h;
  } else {
    const int g = (b - 4096) * 256 + t;
    float e[16];
    float s = 0.f;
#pragma unroll
    for (int k = 0; k < 16; ++k) { e[k] = __expf(w[k * NGATES + g]); s += e[k]; }
    const float inv = 1.0f / s;
#pragma unroll
    for (int k = 0; k < 16; ++k) e[k] *= inv;
    const float P0 = e[8] + e[9] + e[10] + e[11] + e[12] + e[13] + e[14] + e[15];
    const float P1 = e[2] + e[3] + e[6] + e[7] - e[8] - e[9] - e[12] - e[13];
    const float P2 = e[4] + e[5] + e[6] + e[7] - e[8] - e[9] - e[10] - e[11];
    const float P3 = e[1] - e[2] - e[4] - 2.f * e[6] - e[7] + e[8] + 2.f * e[9]
                   + e[11] + e[13] - e[14];
    coeff[g] = make_float4(P0, P1, P2, P3);
  }
}

// ---------------------------------------------------------------------------
// Kernel 2 (v4): READ-SIDE restructure. Previous v0/v2/v3 (write/occupancy
// changes) were all neutral; the invariant was 256B read fragments from
// 64KB-strided rows. v4 tile = [512 n x 64 k]: every wave-read is one FULL
// 1KB contiguous segment (per-instruction max, 4x v3).
//   Phase 1: 4 its of 16 rows; exp -> bf16 k-pairs -> uint4 into LDS
//            tile[col][chunk^ (col>>2 &7)] (conflict-free b128 writes).
//   Phase 2: 8 lanes per bT row -> 128B contiguous stores.
// Col partial sums per 64k-chunk -> psums[32][NCOL]; inv_k folds.
// Grid (NCOL/512, NIN/64) = (32, 32). Dyn LDS 69664B (2 blocks/CU).
// ---------------------------------------------------------------------------
__global__ __launch_bounds__(256) void softmax_t_k(const float* __restrict__ c,
                                                   unsigned short* __restrict__ bT,
                                                   float* __restrict__ psums) {
  extern __shared__ char sm4[];                 // 65536 tile + 4128 red
  char*  tile = sm4;                            // [512 cols][128 B]
  float* red  = (float*)(sm4 + 65536);          // [2][516]
  const int t  = threadIdx.x;
  const int ng = (t & 127) * 4;   // 4 consecutive cols within 512-chunk
  const int kg = t >> 7;          // 0..1: 8-row half
  const int n0 = blockIdx.x * 512;
  const int k0 = blockIdx.y * 64;
  const float* cb = c + (size_t)n0 + ng;
  float s0 = 0.f, s1 = 0.f, s2 = 0.f, s3 = 0.f;

  float4 v[8], nv[8];
  {
    const int r0 = k0 + kg * 8;
#pragma unroll
    for (int d = 0; d < 8; ++d)
      v[d] = *(const float4*)&cb[(size_t)(r0 + d) * NCOL];
  }
  for (int it = 0; it < 4; ++it) {
    if (it < 3) {
      const int r1 = k0 + (it + 1) * 16 + kg * 8;
#pragma unroll
      for (int d = 0; d < 8; ++d)
        nv[d] = *(const float4*)&cb[(size_t)(r1 + d) * NCOL];
    }
    unsigned int u[4][4];   // [col][k-pair]
#pragma unroll
    for (int d2 = 0; d2 < 4; ++d2) {
      float4 e0 = v[2 * d2], e1 = v[2 * d2 + 1];
      unsigned int a0 = f2bf(__expf(e0.x)), b0 = f2bf(__expf(e1.x));
      unsigned int a1 = f2bf(__expf(e0.y)), b1 = f2bf(__expf(e1.y));
      unsigned int a2 = f2bf(__expf(e0.z)), b2 = f2bf(__expf(e1.z));
      unsigned int a3 = f2bf(__expf(e0.w)), b3 = f2bf(__expf(e1.w));
      s0 += bf2f(a0) + bf2f(b0);
      s1 += bf2f(a1) + bf2f(b1);
      s2 += bf2f(a2) + bf2f(b2);
      s3 += bf2f(a3) + bf2f(b3);
      u[0][d2] = a0 | (b0 << 16);
      u[1][d2] = a1 | (b1 << 16);
      u[2][d2] = a2 | (b2 << 16);
      u[3][d2] = a3 | (b3 << 16);
    }
    // chunk of 4 k-pairs (16B) within the 64k row: it*2 + kg (0..7)
    const int chunk = it * 2 + kg;
    const int sw    = (chunk ^ (t & 7)) * 16;   // (col>>2)&7 == t&7 for all j
#pragma unroll
    for (int j = 0; j < 4; ++j) {
      uint4 pk = make_uint4(u[j][0], u[j][1], u[j][2], u[j][3]);
      *(uint4*)&tile[(ng + j) * 128 + sw] = pk;
    }
    if (it < 3) {
#pragma unroll
      for (int d = 0; d < 8; ++d) v[d] = nv[d];
    }
  }
  red[kg * 516 + ng + 0] = s0;
  red[kg * 516 + ng + 1] = s1;
  red[kg * 516 + ng + 2] = s2;
  red[kg * 516 + ng + 3] = s3;
  __syncthreads();

  // Phase 2: 8 lanes per bT row, 128B contiguous stores. 16 passes x 32 rows.
  {
    const int rsub = t >> 3;            // 0..31: row within pass
    const int ch   = t & 7;             // 16B chunk
#pragma unroll
    for (int p = 0; p < 16; ++p) {
      const int row = p * 32 + rsub;
      const int sw  = (ch ^ ((row >> 2) & 7)) * 16;
      uint4 vv = *(const uint4*)&tile[row * 128 + sw];
      *(uint4*)&bT[(size_t)(n0 + row) * NIN + k0 + ch * 8] = vv;
    }
  }
  // column partial sums for this 64k chunk
  {
    const int c0 = 2 * t;
    const float2 tot = make_float2(
        red[c0] + red[516 + c0], red[c0 + 1] + red[516 + c0 + 1]);
    *(float2*)&psums[(size_t)blockIdx.y * NCOL + n0 + c0] = tot;
  }
}

// ---------------------------------------------------------------------------
// Kernel 3: fold 32 k-chunk partials -> invs[n] = 1/sum
// ---------------------------------------------------------------------------
__global__ __launch_bounds__(256) void inv_k(const float* __restrict__ psums,
                                             float* __restrict__ invs) {
  const int n = blockIdx.x * 256 + threadIdx.x;
  float s = 0.f;
#pragma unroll
  for (int q = 0; q < 32; ++q) s += psums[(size_t)q * NCOL + n];
  invs[n] = 1.0f / s;
}

// ---------------------------------------------------------------------------
// Kernel 4: 256x256-tile 8-phase bf16 MFMA GEMM — EXACT round-3 structure
// (proven 134us, VGPR 116, 0 spills, 0 bank conflicts), grid 512.
// Persistent 2-panel reverted (failed twice: spills / +reg pressure).
// Epilogue reads precomputed invs (float2) instead of folding psums.
// ---------------------------------------------------------------------------
#define MFMA_B16(a, b, c) __builtin_amdgcn_mfma_f32_16x16x32_bf16(a, b, c, 0, 0, 0)

__global__ __launch_bounds__(512, 2) void gemm_gate_k(
    const unsigned short* __restrict__ xb,   // [2048][2048] bf16
    const unsigned short* __restrict__ bT,   // [16384][2048] bf16
    const float* __restrict__ invs,          // [16384]
    const float4* __restrict__ coeff,        // [8192]
    float* __restrict__ out) {               // [2048][8192]
  extern __shared__ char smem[];             // 131072 B
  constexpr int NT = 32;                     // K / BK = 2048/64

  const int t  = threadIdx.x;                // 0..511
  const int l  = t & 63;
  const int w  = t >> 6;
  const int wm = w >> 2;                     // 0..1: M half
  const int wn = w & 3;                      // 0..3: N quarter
  const int fr = l & 15;
  const int cq = l >> 4;

  // XCD-bijective swizzle (512 % 8 == 0)
  const int bid = blockIdx.x;
  const int xcd = bid & 7;
  const int loc = bid >> 3;                  // 0..63
  const int m0  = (loc & 7) * 256;
  const int g0  = (xcd * 8 + (loc >> 3)) * 128;

  // ---- stage source offsets (elements), inverse-XOR-swizzled + B-permuted
  uint32_t offA[2][2], offB[2][2];           // [unit][round]
#pragma unroll
  for (int r = 0; r < 2; ++r) {
    const int idx = r * 512 + t;             // 0..1023 -> lds (row, slot)
    const int lr  = idx >> 3;
    const int ch  = (idx & 7) ^ (lr & 7);    // chunk stored at this slot
    const int rA  = (lr & 63) + ((lr >> 6) << 7);       // A1: rows 0-63,128-191
    offA[0][r] = (uint32_t)(m0 + rA) * NIN + ch * 8;
    offA[1][r] = offA[0][r] + (uint32_t)64 * NIN;       // A2: +64
    offB[0][r] = (uint32_t)(2 * (g0 + lr)) * NIN + ch * 8;  // even col
    offB[1][r] = offB[0][r] + NIN;                          // odd col
  }

  auto issueA = [&](int u, int kt) {
    char* d = smem + ((kt & 1) << 16) + (u << 14) + t * 16;
    gload_lds16(xb + offA[u][0] + kt * 64, d);
    gload_lds16(xb + offA[u][1] + kt * 64, d + 8192);
  };
  auto issueB = [&](int u, int kt) {
    char* d = smem + ((kt & 1) << 16) + ((2 + u) << 14) + t * 16;
    gload_lds16(bT + offB[u][0] + kt * 64, d);
    gload_lds16(bT + offB[u][1] + kt * 64, d + 8192);
  };

  // ---- fragment read offsets (row*128, slot = chunk ^ (row&7))
  const int aob = (wm * 64 + fr) * 128;          // + unit*16384 + i*2048
  const int bob = 32768 + (wn * 32 + fr) * 128;  // + unit*16384 + j*2048
  const int sx0 = ((cq)     ^ (fr & 7)) * 16;    // ks=0 slot
  const int sx1 = ((cq + 4) ^ (fr & 7)) * 16;    // ks=1 slot

  f32x4 acc[8][4] = {};
  s16x8 af[8];     // current A half: 4 i x 2 ks
  s16x8 bfr[8];    // [0..3]=B1 (j=0,1 x ks), [4..7]=B2 (j=2,3 x ks)

  // ---- prologue: tile0 full + tile1 {A1,B1,B2}; A2(1) comes at kt=0 ph0
  issueA(0, 0); issueA(1, 0); issueB(0, 0); issueB(1, 0);
  issueA(0, 1); issueB(0, 1); issueB(1, 1);
  asm volatile("s_waitcnt vmcnt(6)" ::: "memory");   // tile0 landed
  asm volatile("s_barrier" ::: "memory");

  for (int kt = 0; kt < NT; ++kt) {
    char* rb = smem + ((kt & 1) << 16);

    // ===== phase 0: (i0-3, j0-1) — read A1 + B1, stage A2(kt+1)
#pragma unroll
    for (int i = 0; i < 4; ++i) {
      af[i * 2 + 0] = *(const s16x8*)(rb + aob + i * 2048 + sx0);
      af[i * 2 + 1] = *(const s16x8*)(rb + aob + i * 2048 + sx1);
    }
#pragma unroll
    for (int j = 0; j < 2; ++j) {
      bfr[j * 2 + 0] = *(const s16x8*)(rb + bob + j * 2048 + sx0);
      bfr[j * 2 + 1] = *(const s16x8*)(rb + bob + j * 2048 + sx1);
    }
    if (kt + 1 < NT) issueA(1, kt + 1);
    asm volatile("s_barrier" ::: "memory");
    asm volatile("s_waitcnt lgkmcnt(0)" ::: "memory");
    __builtin_amdgcn_s_setprio(1);
#pragma unroll
    for (int i = 0; i < 4; ++i)
#pragma unroll
      for (int j = 0; j < 2; ++j) {
        acc[i][j] = MFMA_B16(af[i * 2 + 0], bfr[j * 2 + 0], acc[i][j]);
        acc[i][j] = MFMA_B16(af[i * 2 + 1], bfr[j * 2 + 1], acc[i][j]);
      }
    __builtin_amdgcn_s_setprio(0);
    asm volatile("s_barrier" ::: "memory");

    // ===== phase 1: (i0-3, j2-3) — read B2, stage A1(kt+2)
#pragma unroll
    for (int j = 0; j < 2; ++j) {
      bfr[4 + j * 2 + 0] = *(const s16x8*)(rb + bob + 16384 + j * 2048 + sx0);
      bfr[4 + j * 2 + 1] = *(const s16x8*)(rb + bob + 16384 + j * 2048 + sx1);
    }
    if (kt + 2 < NT) issueA(0, kt + 2);
    asm volatile("s_barrier" ::: "memory");
    asm volatile("s_waitcnt lgkmcnt(0)" ::: "memory");
    __builtin_amdgcn_s_setprio(1);
#pragma unroll
    for (int i = 0; i < 4; ++i)
#pragma unroll
      for (int j = 0; j < 2; ++j) {
        acc[i][2 + j] = MFMA_B16(af[i * 2 + 0], bfr[4 + j * 2 + 0], acc[i][2 + j]);
        acc[i][2 + j] = MFMA_B16(af[i * 2 + 1], bfr[4 + j * 2 + 1], acc[i][2 + j]);
      }
    __builtin_amdgcn_s_setprio(0);
    asm volatile("s_barrier" ::: "memory");

    // ===== phase 2: (i4-7, j2-3) — read A2 into af, stage B1(kt+2)
#pragma unroll
    for (int i = 0; i < 4; ++i) {
      af[i * 2 + 0] = *(const s16x8*)(rb + 16384 + aob + i * 2048 + sx0);
      af[i * 2 + 1] = *(const s16x8*)(rb + 16384 + aob + i * 2048 + sx1);
    }
    if (kt + 2 < NT) issueB(0, kt + 2);
    asm volatile("s_barrier" ::: "memory");
    asm volatile("s_waitcnt lgkmcnt(0)" ::: "memory");
    __builtin_amdgcn_s_setprio(1);
#pragma unroll
    for (int i = 0; i < 4; ++i)
#pragma unroll
      for (int j = 0; j < 2; ++j) {
        acc[4 + i][2 + j] = MFMA_B16(af[i * 2 + 0], bfr[4 + j * 2 + 0], acc[4 + i][2 + j]);
        acc[4 + i][2 + j] = MFMA_B16(af[i * 2 + 1], bfr[4 + j * 2 + 1], acc[4 + i][2 + j]);
      }
    __builtin_amdgcn_s_setprio(0);
    asm volatile("s_barrier" ::: "memory");

    // ===== phase 3: (i4-7, j0-1) — no reads, stage B2(kt+2), counted vmcnt
    if (kt + 2 < NT) issueB(1, kt + 2);
    asm volatile("s_barrier" ::: "memory");
    asm volatile("s_waitcnt lgkmcnt(0)" ::: "memory");
    __builtin_amdgcn_s_setprio(1);
#pragma unroll
    for (int i = 0; i < 4; ++i)
#pragma unroll
      for (int j = 0; j < 2; ++j) {
        acc[4 + i][j] = MFMA_B16(af[i * 2 + 0], bfr[j * 2 + 0], acc[4 + i][j]);
        acc[4 + i][j] = MFMA_B16(af[i * 2 + 1], bfr[j * 2 + 1], acc[4 + i][j]);
      }
    __builtin_amdgcn_s_setprio(0);
    if (kt < NT - 2) {
      asm volatile("s_waitcnt vmcnt(6)" ::: "memory");  // tile kt+1 resident
    } else {
      asm volatile("s_waitcnt vmcnt(0)" ::: "memory");  // drain tail
    }
    asm volatile("s_barrier" ::: "memory");
  }

  // ---- epilogue: normalize (precomputed invs), bilinear gate, store.
#pragma unroll
  for (int j = 0; j < 2; ++j) {
    const int gate = g0 + wn * 32 + j * 16 + fr;
    const float2 iv = *(const float2*)&invs[2 * gate];
    const float4 P  = coeff[gate];
#pragma unroll
    for (int i = 0; i < 8; ++i) {
#pragma unroll
      for (int r = 0; r < 4; ++r) {
        const float A = acc[i][j][r]     * iv.x;
        const float B = acc[i][j + 2][r] * iv.y;
        const float res = P.x + P.y * A + P.z * B + P.w * A * B;
        const int m = m0 + wm * 128 + i * 16 + cq * 4 + r;
        out[(size_t)m * NGATES + gate] = res;
      }
    }
  }
}

// ---------------------------------------------------------------------------
extern "C" void kernel_launch(void* const* d_in, const int* in_sizes, int n_in,
                              void* d_out, int out_size, void* d_ws,
                              size_t ws_size, hipStream_t stream) {
  const float* x = (const float*)d_in[0];   // [2048][2048]
  const float* w = (const float*)d_in[1];   // [16][8192]
  const float* c = (const float*)d_in[2];   // [2048][8192][2]
  float* out = (float*)d_out;               // [2048][8192]
  char* ws = (char*)d_ws;

  unsigned short* xb  = (unsigned short*)(ws);              // 8,388,608 B
  unsigned short* bT  = (unsigned short*)(ws + 8388608);    // 67,108,864 B
  float*          psv = (float*)(ws + 75497472);            // 2,097,152 B
  float*          ivv = (float*)(ws + 77594624);            // 65,536 B
  float4*         cf  = (float4*)(ws + 77660160);           // 131,072 B

  static bool attr_done = false;
  if (!attr_done) {
    (void)hipFuncSetAttribute(reinterpret_cast<const void*>(gemm_gate_k),
                              hipFuncAttributeMaxDynamicSharedMemorySize,
                              131072);
    (void)hipFuncSetAttribute(reinterpret_cast<const void*>(softmax_t_k),
                              hipFuncAttributeMaxDynamicSharedMemorySize,
                              69664);
    attr_done = true;
  }

  pre_k<<<4128, 256, 0, stream>>>((const float4*)x, (ushort4*)xb, w, cf);
  dim3 sg(NCOL / 512, NIN / 64);
  softmax_t_k<<<sg, 256, 69664, stream>>>(c, bT, psv);
  inv_k<<<NCOL / 256, 256, 0, stream>>>(psv, ivv);
  gemm_gate_k<<<512, 512, 131072, stream>>>(xb, bT, ivv, cf, out);
}